// Round 1
// baseline (1181.384 us; speedup 1.0000x reference)
//
#include <hip/hip_runtime.h>

#define N_AUTHOR 100000
#define N_FOS    30000
#define N_INST   8000
#define N_PAPER  200000

typedef __attribute__((ext_vector_type(8))) short short8v;
typedef __attribute__((ext_vector_type(4))) float float4v;

__device__ __forceinline__ unsigned short f2bf(float f) {
  unsigned u = __float_as_uint(f);
  u = u + 0x7fffu + ((u >> 16) & 1u);
  return (unsigned short)(u >> 16);
}

// ---------------- workspace layout (bytes) ----------------
// cnt:    838000 int   @ 0
// offs:   838000 int   @ 3352000
// cursor: 838000 int   @ 6704000
// btot:   1024 int     @ 10056000
// csr:    3300000 int  @ 10060096
// wt:     11*16384 u16 @ 23260096   (end 23620544)
#define O_CNT    0
#define O_OFFS   3352000
#define O_CURSOR 6704000
#define O_BTOT   10056000
#define O_CSR    10060096
#define O_WT     23260096
#define NCNT     838000
#define NEDGE_T  3300000

struct RelTab { const int* src; const int* dst; int E; int base; };
struct Rels { RelTab r[7]; };
struct WPtrs { const float* w[11]; };

// transpose + bf16-convert weights: W[k][n] fp32 -> WT[n][k] bf16
__global__ void conv_w(WPtrs P, unsigned short* __restrict__ wt) {
  int idx = blockIdx.x * 256 + threadIdx.x;
  if (idx >= 11 * 16384) return;
  int mat = idx >> 14, rem = idx & 16383;
  int k = rem >> 7, n = rem & 127;
  float v = P.w[mat][rem];
  wt[mat * 16384 + n * 128 + k] = f2bf(v);
}

__global__ void count_k(Rels R, int* __restrict__ cnt) {
  int gsz = gridDim.x * blockDim.x;
  int gtid = blockIdx.x * blockDim.x + threadIdx.x;
  for (int rr = 0; rr < 7; ++rr) {
    const int* dst = R.r[rr].dst;
    int E = R.r[rr].E, base = R.r[rr].base;
    for (int e = gtid; e < E; e += gsz) atomicAdd(&cnt[base + dst[e]], 1);
  }
}

// block-level exclusive scan over 2048 elements/block
__global__ void scan1(const int* __restrict__ cnt, int* __restrict__ offs,
                      int* __restrict__ btot, int n) {
  __shared__ int sh[256];
  int tid = threadIdx.x;
  int base = blockIdx.x * 2048 + tid * 8;
  int v[8]; int s = 0;
  #pragma unroll
  for (int i = 0; i < 8; ++i) { v[i] = (base + i < n) ? cnt[base + i] : 0; s += v[i]; }
  sh[tid] = s; __syncthreads();
  for (int off = 1; off < 256; off <<= 1) {
    int t = (tid >= off) ? sh[tid - off] : 0;
    __syncthreads();
    sh[tid] += t;
    __syncthreads();
  }
  int excl = sh[tid] - s;
  if (tid == 255) btot[blockIdx.x] = sh[255];
  int run = excl;
  #pragma unroll
  for (int i = 0; i < 8; ++i) { if (base + i < n) offs[base + i] = run; run += v[i]; }
}

__global__ void scan2(int* __restrict__ btot, int nb) {
  __shared__ int sh[512];
  int tid = threadIdx.x;
  int v = (tid < nb) ? btot[tid] : 0;
  sh[tid] = v; __syncthreads();
  for (int off = 1; off < 512; off <<= 1) {
    int t = (tid >= off) ? sh[tid - off] : 0;
    __syncthreads();
    sh[tid] += t;
    __syncthreads();
  }
  if (tid < nb) btot[tid] = sh[tid] - v;  // exclusive
}

__global__ void scan3(int* __restrict__ offs, int* __restrict__ cursor,
                      const int* __restrict__ btot, int n) {
  int gsz = gridDim.x * blockDim.x;
  for (int idx = blockIdx.x * blockDim.x + threadIdx.x; idx < n; idx += gsz) {
    int b = idx >> 11;
    int v = offs[idx] + btot[b];
    offs[idx] = v;
    cursor[idx] = v;
  }
}

__global__ void fill_k(Rels R, int* __restrict__ cursor, int* __restrict__ csr) {
  int gsz = gridDim.x * blockDim.x;
  int gtid = blockIdx.x * blockDim.x + threadIdx.x;
  for (int rr = 0; rr < 7; ++rr) {
    const int* src = R.r[rr].src;
    const int* dst = R.r[rr].dst;
    int E = R.r[rr].E, base = R.r[rr].base;
    for (int e = gtid; e < E; e += gsz) {
      int p = atomicAdd(&cursor[base + dst[e]], 1);
      csr[p] = src[e];
    }
  }
}

struct GemmSrc { const float* x; const unsigned short* wt; int cntBase; };
struct GemmArgs {
  GemmSrc s[4];
  int nsrc;
  const float* bias;
  const int* offs;
  const int* cnt;
  const int* csr;
  float* out;
  int n;
};

// out[64 rows x 128] = sum_kb A_kb @ W_kb + bias, A_kb staged into LDS as bf16.
// kb==root: A = x rows. kb==relation: A = mean of gathered x_src rows (CSR).
__global__ __launch_bounds__(256, 2) void fused_gemm(GemmArgs A) {
  __shared__ unsigned short a_lds[64 * 128];
  __shared__ unsigned short w_lds[128 * 128];
  const int tid = threadIdx.x;
  const int wv = tid >> 6, lane = tid & 63;
  const int rb = blockIdx.x * 64;

  float4v acc[8];
  #pragma unroll
  for (int i = 0; i < 8; ++i) acc[i] = (float4v)0.0f;

  for (int kb = 0; kb < A.nsrc; ++kb) {
    const GemmSrc S = A.s[kb];
    // ---- stage W (WT[n][k] bf16, 16384 elems) into swizzled LDS ----
    #pragma unroll
    for (int i = 0; i < 8; ++i) {
      int c = tid + i * 256;               // chunk of 8 bf16
      int nr = c >> 4, k0 = (c & 15) * 8;
      uint4 v = *(const uint4*)(S.wt + (size_t)c * 8);
      int byte = nr * 256 + k0 * 2; byte ^= (nr & 7) << 4;
      *(uint4*)((char*)w_lds + byte) = v;
    }
    // ---- stage A ----
    if (S.cntBase < 0) {
      // root: direct rows, fp32 -> bf16
      #pragma unroll
      for (int i = 0; i < 4; ++i) {
        int c = tid + i * 256;             // chunk of 8 floats
        int r = c >> 4, c0 = (c & 15) * 8;
        int g = rb + r;
        short8v hv;
        if (g < A.n) {
          float4 v0 = *(const float4*)(S.x + (size_t)g * 128 + c0);
          float4 v1 = *(const float4*)(S.x + (size_t)g * 128 + c0 + 4);
          hv[0] = (short)f2bf(v0.x); hv[1] = (short)f2bf(v0.y);
          hv[2] = (short)f2bf(v0.z); hv[3] = (short)f2bf(v0.w);
          hv[4] = (short)f2bf(v1.x); hv[5] = (short)f2bf(v1.y);
          hv[6] = (short)f2bf(v1.z); hv[7] = (short)f2bf(v1.w);
        } else {
          hv = (short8v)0;
        }
        int byte = r * 256 + c0 * 2; byte ^= (r & 7) << 4;
        *(short8v*)((char*)a_lds + byte) = hv;
      }
    } else {
      // relation: CSR gather + mean. wave wv owns rows wv*16..wv*16+15.
      for (int rr = 0; rr < 16; ++rr) {
        int r = wv * 16 + rr, g = rb + r;
        float ax0 = 0.f, ay0 = 0.f, ax1 = 0.f, ay1 = 0.f;
        float ax2 = 0.f, ay2 = 0.f, ax3 = 0.f, ay3 = 0.f;
        int deg = 0;
        if (g < A.n) {
          int gd = S.cntBase + g;
          int st = A.offs[gd];
          deg = A.cnt[gd];
          int j = 0;
          for (; j + 4 <= deg; j += 4) {
            int s0 = A.csr[st + j], s1 = A.csr[st + j + 1];
            int s2 = A.csr[st + j + 2], s3 = A.csr[st + j + 3];
            float2 v0 = *(const float2*)(S.x + (size_t)s0 * 128 + lane * 2);
            float2 v1 = *(const float2*)(S.x + (size_t)s1 * 128 + lane * 2);
            float2 v2 = *(const float2*)(S.x + (size_t)s2 * 128 + lane * 2);
            float2 v3 = *(const float2*)(S.x + (size_t)s3 * 128 + lane * 2);
            ax0 += v0.x; ay0 += v0.y; ax1 += v1.x; ay1 += v1.y;
            ax2 += v2.x; ay2 += v2.y; ax3 += v3.x; ay3 += v3.y;
          }
          for (; j < deg; ++j) {
            int s0 = A.csr[st + j];
            float2 v0 = *(const float2*)(S.x + (size_t)s0 * 128 + lane * 2);
            ax0 += v0.x; ay0 += v0.y;
          }
        }
        float sc = 1.0f / (float)((deg > 0) ? deg : 1);
        float vx = (ax0 + ax1 + ax2 + ax3) * sc;
        float vy = (ay0 + ay1 + ay2 + ay3) * sc;
        unsigned pack = (unsigned)f2bf(vx) | ((unsigned)f2bf(vy) << 16);
        int byte = r * 256 + lane * 4; byte ^= (r & 7) << 4;
        *(unsigned*)((char*)a_lds + byte) = pack;
      }
    }
    __syncthreads();
    // ---- MFMA: 16x16x32 bf16, wave wv computes rows wv*16..+15, all 128 cols
    short8v af[4];
    #pragma unroll
    for (int ks = 0; ks < 4; ++ks) {
      int r = wv * 16 + (lane & 15);
      int ch = ks * 4 + (lane >> 4);
      int byte = r * 256 + ch * 16; byte ^= (r & 7) << 4;
      af[ks] = *(const short8v*)((const char*)a_lds + byte);
    }
    #pragma unroll
    for (int ct = 0; ct < 8; ++ct) {
      #pragma unroll
      for (int ks = 0; ks < 4; ++ks) {
        int nr = ct * 16 + (lane & 15);
        int ch = ks * 4 + (lane >> 4);
        int byte = nr * 256 + ch * 16; byte ^= (nr & 7) << 4;
        short8v bf = *(const short8v*)((const char*)w_lds + byte);
        acc[ct] = __builtin_amdgcn_mfma_f32_16x16x32_bf16(af[ks], bf, acc[ct], 0, 0, 0);
      }
    }
    __syncthreads();
  }
  // ---- epilogue: D mapping col=lane&15, row=(lane>>4)*4+i ----
  #pragma unroll
  for (int ct = 0; ct < 8; ++ct) {
    #pragma unroll
    for (int i = 0; i < 4; ++i) {
      int row = wv * 16 + (lane >> 4) * 4 + i;
      int g = rb + row;
      if (g < A.n) {
        int col = ct * 16 + (lane & 15);
        A.out[(size_t)g * 128 + col] = acc[ct][i] + A.bias[col];
      }
    }
  }
}

extern "C" void kernel_launch(void* const* d_in, const int* in_sizes, int n_in,
                              void* d_out, int out_size, void* d_ws, size_t ws_size,
                              hipStream_t stream) {
  const float* x_author = (const float*)d_in[0];
  const float* x_fos    = (const float*)d_in[1];
  const float* x_inst   = (const float*)d_in[2];
  const float* x_paper  = (const float*)d_in[3];

  Rels R;
  const int E[7]  = {150000, 150000, 500000, 500000, 1000000, 500000, 500000};
  const int ND[7] = {N_INST, N_AUTHOR, N_PAPER, N_AUTHOR, N_PAPER, N_FOS, N_PAPER};
  int base = 0;
  for (int r = 0; r < 7; ++r) {
    R.r[r].src = (const int*)d_in[4 + 2 * r];
    R.r[r].dst = (const int*)d_in[5 + 2 * r];
    R.r[r].E = E[r];
    R.r[r].base = base;
    base += ND[r];
  }

  char* ws = (char*)d_ws;
  int* cnt    = (int*)(ws + O_CNT);
  int* offs   = (int*)(ws + O_OFFS);
  int* cursor = (int*)(ws + O_CURSOR);
  int* btot   = (int*)(ws + O_BTOT);
  int* csr    = (int*)(ws + O_CSR);
  unsigned short* wt = (unsigned short*)(ws + O_WT);

  WPtrs WP;
  WP.w[0] = (const float*)d_in[18];  // W_root_author
  WP.w[1] = (const float*)d_in[20];  // W_root_fos
  WP.w[2] = (const float*)d_in[22];  // W_root_inst
  WP.w[3] = (const float*)d_in[24];  // W_root_paper
  for (int r = 0; r < 7; ++r) WP.w[4 + r] = (const float*)d_in[26 + r];

  conv_w<<<704, 256, 0, stream>>>(WP, wt);
  hipMemsetAsync(cnt, 0, (size_t)NCNT * 4, stream);
  count_k<<<1024, 256, 0, stream>>>(R, cnt);
  scan1<<<410, 256, 0, stream>>>(cnt, offs, btot, NCNT);
  scan2<<<1, 512, 0, stream>>>(btot, 410);
  scan3<<<1024, 256, 0, stream>>>(offs, cursor, btot, NCNT);
  fill_k<<<1024, 256, 0, stream>>>(R, cursor, csr);

  float* out = (float*)d_out;
  const int B_AFF = 0, B_ITA = 8000, B_WRITES = 108000, B_PTA = 308000,
            B_CITES = 408000, B_TOPIC = 608000, B_FTP = 638000;

  GemmArgs ga;
  ga.offs = offs; ga.cnt = cnt; ga.csr = csr;
  for (int i = 0; i < 4; ++i) ga.s[i] = GemmSrc{nullptr, nullptr, 0};

  // author: root + ita(inst->author) + pta(paper->author)
  ga.s[0] = GemmSrc{x_author, wt + 0 * 16384, -1};
  ga.s[1] = GemmSrc{x_inst,   wt + 5 * 16384, B_ITA};
  ga.s[2] = GemmSrc{x_paper,  wt + 7 * 16384, B_PTA};
  ga.nsrc = 3; ga.bias = (const float*)d_in[19];
  ga.out = out; ga.n = N_AUTHOR;
  fused_gemm<<<(N_AUTHOR + 63) / 64, 256, 0, stream>>>(ga);

  // fos: root + topic(paper->fos)
  ga.s[0] = GemmSrc{x_fos,   wt + 1 * 16384, -1};
  ga.s[1] = GemmSrc{x_paper, wt + 9 * 16384, B_TOPIC};
  ga.nsrc = 2; ga.bias = (const float*)d_in[21];
  ga.out = out + (size_t)100000 * 128; ga.n = N_FOS;
  fused_gemm<<<(N_FOS + 63) / 64, 256, 0, stream>>>(ga);

  // inst: root + aff(author->inst)
  ga.s[0] = GemmSrc{x_inst,   wt + 2 * 16384, -1};
  ga.s[1] = GemmSrc{x_author, wt + 4 * 16384, B_AFF};
  ga.nsrc = 2; ga.bias = (const float*)d_in[23];
  ga.out = out + (size_t)130000 * 128; ga.n = N_INST;
  fused_gemm<<<(N_INST + 63) / 64, 256, 0, stream>>>(ga);

  // paper: root + writes(author->paper) + cites(paper->paper) + ftp(fos->paper)
  ga.s[0] = GemmSrc{x_paper,  wt + 3 * 16384, -1};
  ga.s[1] = GemmSrc{x_author, wt + 6 * 16384, B_WRITES};
  ga.s[2] = GemmSrc{x_paper,  wt + 8 * 16384, B_CITES};
  ga.s[3] = GemmSrc{x_fos,    wt + 10 * 16384, B_FTP};
  ga.nsrc = 4; ga.bias = (const float*)d_in[25];
  ga.out = out + (size_t)138000 * 128; ga.n = N_PAPER;
  fused_gemm<<<(N_PAPER + 63) / 64, 256, 0, stream>>>(ga);
}

// Round 2
// 917.238 us; speedup vs baseline: 1.2880x; 1.2880x over previous
//
#include <hip/hip_runtime.h>

#define N_AUTHOR 100000
#define N_FOS    30000
#define N_INST   8000
#define N_PAPER  200000

typedef __attribute__((ext_vector_type(8))) short short8v;
typedef __attribute__((ext_vector_type(4))) float float4v;

__device__ __forceinline__ unsigned short f2bf(float f) {
  unsigned u = __float_as_uint(f);
  u = u + 0x7fffu + ((u >> 16) & 1u);
  return (unsigned short)(u >> 16);
}

// ---------------- workspace layout (bytes) ----------------
#define O_CNT    0
#define O_OFFS   3352000
#define O_CURSOR 6704000
#define O_BTOT   10056000
#define O_CSR    10060096
#define O_WT     23260096
#define NCNT     838000

struct RelTab { const int* src; const int* dst; int E; int base; };
struct Rels { RelTab r[7]; };
struct WPtrs { const float* w[11]; };

// transpose + bf16-convert weights: W[k][n] fp32 -> WT[n][k] bf16
__global__ void conv_w(WPtrs P, unsigned short* __restrict__ wt) {
  int idx = blockIdx.x * 256 + threadIdx.x;
  if (idx >= 11 * 16384) return;
  int mat = idx >> 14, rem = idx & 16383;
  int k = rem >> 7, n = rem & 127;
  float v = P.w[mat][rem];
  wt[mat * 16384 + n * 128 + k] = f2bf(v);
}

__global__ void count_k(Rels R, int* __restrict__ cnt) {
  int gsz = gridDim.x * blockDim.x;
  int gtid = blockIdx.x * blockDim.x + threadIdx.x;
  for (int rr = 0; rr < 7; ++rr) {
    const int* dst = R.r[rr].dst;
    int E = R.r[rr].E, base = R.r[rr].base;
    for (int e = gtid; e < E; e += gsz) atomicAdd(&cnt[base + dst[e]], 1);
  }
}

__global__ void scan1(const int* __restrict__ cnt, int* __restrict__ offs,
                      int* __restrict__ btot, int n) {
  __shared__ int sh[256];
  int tid = threadIdx.x;
  int base = blockIdx.x * 2048 + tid * 8;
  int v[8]; int s = 0;
  #pragma unroll
  for (int i = 0; i < 8; ++i) { v[i] = (base + i < n) ? cnt[base + i] : 0; s += v[i]; }
  sh[tid] = s; __syncthreads();
  for (int off = 1; off < 256; off <<= 1) {
    int t = (tid >= off) ? sh[tid - off] : 0;
    __syncthreads();
    sh[tid] += t;
    __syncthreads();
  }
  int excl = sh[tid] - s;
  if (tid == 255) btot[blockIdx.x] = sh[255];
  int run = excl;
  #pragma unroll
  for (int i = 0; i < 8; ++i) { if (base + i < n) offs[base + i] = run; run += v[i]; }
}

__global__ void scan2(int* __restrict__ btot, int nb) {
  __shared__ int sh[512];
  int tid = threadIdx.x;
  int v = (tid < nb) ? btot[tid] : 0;
  sh[tid] = v; __syncthreads();
  for (int off = 1; off < 512; off <<= 1) {
    int t = (tid >= off) ? sh[tid - off] : 0;
    __syncthreads();
    sh[tid] += t;
    __syncthreads();
  }
  if (tid < nb) btot[tid] = sh[tid] - v;  // exclusive
}

__global__ void scan3(int* __restrict__ offs, int* __restrict__ cursor,
                      const int* __restrict__ btot, int n) {
  int gsz = gridDim.x * blockDim.x;
  for (int idx = blockIdx.x * blockDim.x + threadIdx.x; idx < n; idx += gsz) {
    int b = idx >> 11;
    int v = offs[idx] + btot[b];
    offs[idx] = v;
    cursor[idx] = v;
  }
}

__global__ void fill_k(Rels R, int* __restrict__ cursor, int* __restrict__ csr) {
  int gsz = gridDim.x * blockDim.x;
  int gtid = blockIdx.x * blockDim.x + threadIdx.x;
  for (int rr = 0; rr < 7; ++rr) {
    const int* src = R.r[rr].src;
    const int* dst = R.r[rr].dst;
    int E = R.r[rr].E, base = R.r[rr].base;
    for (int e = gtid; e < E; e += gsz) {
      int p = atomicAdd(&cursor[base + dst[e]], 1);
      csr[p] = src[e];
    }
  }
}

struct GemmSrc { const float* x; const unsigned short* wt; int cntBase; };
struct TypeArgs {
  GemmSrc s[4];
  int nsrc;
  int bstart;     // first block id of this type
  int n;          // rows of this type
  const float* bias;
  float* out;
};
struct AllArgs {
  TypeArgs t[4];
  const int* offs;
  const int* cnt;
  const int* csr;
};

// One block = 64 output rows x 128 cols of one node type.
// A (bf16) staged in LDS; B fragments loaded directly from global WT (L1-hot).
__global__ __launch_bounds__(256, 4) void rgcn_gemm(AllArgs A) {
  __shared__ unsigned short a_lds[64 * 128];
  const int tid = threadIdx.x;
  const int wv = tid >> 6, lane = tid & 63;
  const int q = lane >> 4;            // quarter-wave id 0..3
  const int c0 = (lane & 15) * 8;     // 8-float column slice owned in gather

  int bid = blockIdx.x;
  int ty = (bid >= A.t[3].bstart) ? 3 : (bid >= A.t[2].bstart) ? 2
         : (bid >= A.t[1].bstart) ? 1 : 0;
  const TypeArgs& T = A.t[ty];
  const int rb = (bid - T.bstart) * 64;
  const int n = T.n;

  float4v acc[8];
  #pragma unroll
  for (int i = 0; i < 8; ++i) acc[i] = (float4v)0.0f;

  for (int kb = 0; kb < T.nsrc; ++kb) {
    const GemmSrc S = T.s[kb];
    // ---- stage A into swizzled LDS (bf16) ----
    if (S.cntBase < 0) {
      // root: direct rows, fp32 -> bf16. 256 threads x 4 chunks of 8 floats.
      #pragma unroll
      for (int i = 0; i < 4; ++i) {
        int c = tid + i * 256;
        int r = c >> 4, cc = (c & 15) * 8;
        int g = rb + r;
        short8v hv;
        if (g < n) {
          float4 v0 = *(const float4*)(S.x + (size_t)g * 128 + cc);
          float4 v1 = *(const float4*)(S.x + (size_t)g * 128 + cc + 4);
          hv[0] = (short)f2bf(v0.x); hv[1] = (short)f2bf(v0.y);
          hv[2] = (short)f2bf(v0.z); hv[3] = (short)f2bf(v0.w);
          hv[4] = (short)f2bf(v1.x); hv[5] = (short)f2bf(v1.y);
          hv[6] = (short)f2bf(v1.z); hv[7] = (short)f2bf(v1.w);
        } else {
          hv = (short8v)0;
        }
        int byte = r * 256 + cc * 2; byte ^= (r & 7) << 4;
        *(short8v*)((char*)a_lds + byte) = hv;
      }
    } else {
      // relation: quarter-wave per row; 16 rows in flight per block per round.
      int stA[4], dgA[4];
      #pragma unroll
      for (int rd = 0; rd < 4; ++rd) {
        int r = wv * 16 + rd * 4 + q;
        int g = rb + r;
        int gc = (g < n) ? g : (n - 1);
        int gd = S.cntBase + gc;
        stA[rd] = A.offs[gd];
        dgA[rd] = (g < n) ? A.cnt[gd] : 0;
      }
      #pragma unroll
      for (int rd = 0; rd < 4; ++rd) {
        int r = wv * 16 + rd * 4 + q;
        int st = stA[rd], deg = dgA[rd];
        float a0 = 0.f, a1 = 0.f, a2 = 0.f, a3 = 0.f;
        float a4 = 0.f, a5 = 0.f, a6 = 0.f, a7 = 0.f;
        int j = 0;
        for (; j + 2 <= deg; j += 2) {
          int s0 = A.csr[st + j], s1 = A.csr[st + j + 1];
          const float* p0 = S.x + (size_t)s0 * 128 + c0;
          const float* p1 = S.x + (size_t)s1 * 128 + c0;
          float4 u0 = *(const float4*)p0;
          float4 u1 = *(const float4*)(p0 + 4);
          float4 v0 = *(const float4*)p1;
          float4 v1 = *(const float4*)(p1 + 4);
          a0 += u0.x + v0.x; a1 += u0.y + v0.y;
          a2 += u0.z + v0.z; a3 += u0.w + v0.w;
          a4 += u1.x + v1.x; a5 += u1.y + v1.y;
          a6 += u1.z + v1.z; a7 += u1.w + v1.w;
        }
        if (j < deg) {
          int s0 = A.csr[st + j];
          const float* p0 = S.x + (size_t)s0 * 128 + c0;
          float4 u0 = *(const float4*)p0;
          float4 u1 = *(const float4*)(p0 + 4);
          a0 += u0.x; a1 += u0.y; a2 += u0.z; a3 += u0.w;
          a4 += u1.x; a5 += u1.y; a6 += u1.z; a7 += u1.w;
        }
        float sc = 1.0f / (float)((deg > 0) ? deg : 1);
        short8v hv;
        hv[0] = (short)f2bf(a0 * sc); hv[1] = (short)f2bf(a1 * sc);
        hv[2] = (short)f2bf(a2 * sc); hv[3] = (short)f2bf(a3 * sc);
        hv[4] = (short)f2bf(a4 * sc); hv[5] = (short)f2bf(a5 * sc);
        hv[6] = (short)f2bf(a6 * sc); hv[7] = (short)f2bf(a7 * sc);
        int byte = r * 256 + c0 * 2; byte ^= (r & 7) << 4;
        *(short8v*)((char*)a_lds + byte) = hv;
      }
    }
    __syncthreads();
    // ---- A fragments from LDS ----
    short8v af[4];
    #pragma unroll
    for (int ks = 0; ks < 4; ++ks) {
      int r = wv * 16 + (lane & 15);
      int ch = ks * 4 + (lane >> 4);
      int byte = r * 256 + ch * 16; byte ^= (r & 7) << 4;
      af[ks] = *(const short8v*)((const char*)a_lds + byte);
    }
    // ---- B fragments straight from global (L1-hot), then MFMA ----
    const unsigned short* wbase = S.wt + (size_t)(lane & 15) * 128
                                + (size_t)(lane >> 4) * 8;
    #pragma unroll
    for (int ct = 0; ct < 8; ++ct) {
      short8v bfr[4];
      #pragma unroll
      for (int ks = 0; ks < 4; ++ks)
        bfr[ks] = *(const short8v*)(wbase + (size_t)ct * 16 * 128 + ks * 32);
      #pragma unroll
      for (int ks = 0; ks < 4; ++ks)
        acc[ct] = __builtin_amdgcn_mfma_f32_16x16x32_bf16(af[ks], bfr[ks], acc[ct], 0, 0, 0);
    }
    __syncthreads();
  }
  // ---- epilogue ----
  #pragma unroll
  for (int ct = 0; ct < 8; ++ct) {
    #pragma unroll
    for (int i = 0; i < 4; ++i) {
      int row = wv * 16 + (lane >> 4) * 4 + i;
      int g = rb + row;
      if (g < n) {
        int col = ct * 16 + (lane & 15);
        T.out[(size_t)g * 128 + col] = acc[ct][i] + T.bias[col];
      }
    }
  }
}

extern "C" void kernel_launch(void* const* d_in, const int* in_sizes, int n_in,
                              void* d_out, int out_size, void* d_ws, size_t ws_size,
                              hipStream_t stream) {
  const float* x_author = (const float*)d_in[0];
  const float* x_fos    = (const float*)d_in[1];
  const float* x_inst   = (const float*)d_in[2];
  const float* x_paper  = (const float*)d_in[3];

  Rels R;
  const int E[7]  = {150000, 150000, 500000, 500000, 1000000, 500000, 500000};
  const int ND[7] = {N_INST, N_AUTHOR, N_PAPER, N_AUTHOR, N_PAPER, N_FOS, N_PAPER};
  int base = 0;
  for (int r = 0; r < 7; ++r) {
    R.r[r].src = (const int*)d_in[4 + 2 * r];
    R.r[r].dst = (const int*)d_in[5 + 2 * r];
    R.r[r].E = E[r];
    R.r[r].base = base;
    base += ND[r];
  }

  char* ws = (char*)d_ws;
  int* cnt    = (int*)(ws + O_CNT);
  int* offs   = (int*)(ws + O_OFFS);
  int* cursor = (int*)(ws + O_CURSOR);
  int* btot   = (int*)(ws + O_BTOT);
  int* csr    = (int*)(ws + O_CSR);
  unsigned short* wt = (unsigned short*)(ws + O_WT);

  WPtrs WP;
  WP.w[0] = (const float*)d_in[18];
  WP.w[1] = (const float*)d_in[20];
  WP.w[2] = (const float*)d_in[22];
  WP.w[3] = (const float*)d_in[24];
  for (int r = 0; r < 7; ++r) WP.w[4 + r] = (const float*)d_in[26 + r];

  conv_w<<<704, 256, 0, stream>>>(WP, wt);
  hipMemsetAsync(cnt, 0, (size_t)NCNT * 4, stream);
  count_k<<<1024, 256, 0, stream>>>(R, cnt);
  scan1<<<410, 256, 0, stream>>>(cnt, offs, btot, NCNT);
  scan2<<<1, 512, 0, stream>>>(btot, 410);
  scan3<<<1024, 256, 0, stream>>>(offs, cursor, btot, NCNT);
  fill_k<<<1024, 256, 0, stream>>>(R, cursor, csr);

  float* out = (float*)d_out;
  const int B_AFF = 0, B_ITA = 8000, B_WRITES = 108000, B_PTA = 308000,
            B_CITES = 408000, B_TOPIC = 608000, B_FTP = 638000;

  AllArgs A;
  A.offs = offs; A.cnt = cnt; A.csr = csr;
  for (int t = 0; t < 4; ++t)
    for (int i = 0; i < 4; ++i) A.t[t].s[i] = GemmSrc{nullptr, nullptr, 0};

  const int NB_AUTHOR = (N_AUTHOR + 63) / 64;   // 1563
  const int NB_FOS    = (N_FOS + 63) / 64;      // 469
  const int NB_INST   = (N_INST + 63) / 64;     // 125
  const int NB_PAPER  = (N_PAPER + 63) / 64;    // 3125

  // author
  A.t[0].s[0] = GemmSrc{x_author, wt + 0 * 16384, -1};
  A.t[0].s[1] = GemmSrc{x_inst,   wt + 5 * 16384, B_ITA};
  A.t[0].s[2] = GemmSrc{x_paper,  wt + 7 * 16384, B_PTA};
  A.t[0].nsrc = 3; A.t[0].bstart = 0; A.t[0].n = N_AUTHOR;
  A.t[0].bias = (const float*)d_in[19]; A.t[0].out = out;
  // fos
  A.t[1].s[0] = GemmSrc{x_fos,   wt + 1 * 16384, -1};
  A.t[1].s[1] = GemmSrc{x_paper, wt + 9 * 16384, B_TOPIC};
  A.t[1].nsrc = 2; A.t[1].bstart = NB_AUTHOR; A.t[1].n = N_FOS;
  A.t[1].bias = (const float*)d_in[21]; A.t[1].out = out + (size_t)100000 * 128;
  // inst
  A.t[2].s[0] = GemmSrc{x_inst,   wt + 2 * 16384, -1};
  A.t[2].s[1] = GemmSrc{x_author, wt + 4 * 16384, B_AFF};
  A.t[2].nsrc = 2; A.t[2].bstart = NB_AUTHOR + NB_FOS; A.t[2].n = N_INST;
  A.t[2].bias = (const float*)d_in[23]; A.t[2].out = out + (size_t)130000 * 128;
  // paper
  A.t[3].s[0] = GemmSrc{x_paper,  wt + 3 * 16384, -1};
  A.t[3].s[1] = GemmSrc{x_author, wt + 6 * 16384, B_WRITES};
  A.t[3].s[2] = GemmSrc{x_paper,  wt + 8 * 16384, B_CITES};
  A.t[3].s[3] = GemmSrc{x_fos,    wt + 10 * 16384, B_FTP};
  A.t[3].nsrc = 4; A.t[3].bstart = NB_AUTHOR + NB_FOS + NB_INST; A.t[3].n = N_PAPER;
  A.t[3].bias = (const float*)d_in[25]; A.t[3].out = out + (size_t)138000 * 128;

  const int NB_TOTAL = NB_AUTHOR + NB_FOS + NB_INST + NB_PAPER;  // 5282
  rgcn_gemm<<<NB_TOTAL, 256, 0, stream>>>(A);
}